// Round 1
// baseline (72.517 us; speedup 1.0000x reference)
//
#include <hip/hip_runtime.h>
#include <math.h>

// HistDRDoubleConv on gfx950.
// B=8, Cin=Cmid=Cout=8, H=W=256, R=8. Pool: k=86, s=85 -> 3x3.
// Pipeline: pool(x)->K1 ; conv1(x,K1[argmax hist])+BN+ReLU -> y1 ;
//           pool(y1)->K2 ; conv2(y1,K2[regmap])+BN+ReLU -> out.

#define HWPX 65536   // 256*256
#define HDIM 256

// ---------------- pool: one block per (b,c,i,j) window (576 blocks) ----------
__global__ __launch_bounds__(256) void pool_kernel(const float* __restrict__ in,
                                                   float* __restrict__ p) {
  int idx = blockIdx.x;            // (b*8+c)*9 + ij
  int ij = idx % 9; int bc = idx / 9;
  int i = ij / 3, j = ij - i * 3;
  const float* src = in + (size_t)bc * HWPX + (i * 85) * HDIM + (j * 85);
  float s = 0.f;
  for (int t = threadIdx.x; t < 86 * 86; t += 256) {
    int dy = t / 86, dx = t - dy * 86;
    s += src[dy * HDIM + dx];
  }
  __shared__ float red[256];
  red[threadIdx.x] = s;
  __syncthreads();
  for (int off = 128; off > 0; off >>= 1) {
    if (threadIdx.x < off) red[threadIdx.x] += red[threadIdx.x + off];
    __syncthreads();
  }
  if (threadIdx.x == 0) p[idx] = red[0] * (1.f / 7396.f);
}

// ---------------- build dynamic kernels: one block per (b,r) -----------------
// Output layout per (b,r): Kg[(b*8+r)*576 + (ci*9+tap)*8 + oc], bb baked into
// every tap (reference adds bb to each kernel weight, not as a conv bias).
__global__ __launch_bounds__(128) void make_kernels(const float* __restrict__ p,
                                                    const float* __restrict__ wa,
                                                    const float* __restrict__ ba,
                                                    const float* __restrict__ wb,
                                                    const float* __restrict__ bb,
                                                    float* __restrict__ Kg) {
  int b = blockIdx.x >> 3;
  int r = blockIdx.x & 7;
  __shared__ float h[72];          // [cc][tap]
  int t = threadIdx.x;
  if (t < 72) {
    int cc = t / 9, ij = t - cc * 9;
    int o = r * 8 + cc;
    float z = ba[o];
#pragma unroll
    for (int c = 0; c < 8; c++) z += p[(b * 8 + c) * 9 + ij] * wa[o * 8 + c];
    h[cc * 9 + ij] = 1.f / (1.f + expf(-z));
  }
  __syncthreads();
  for (int u = t; u < 576; u += 128) {
    int oc = u & 7;
    int vv = u >> 3;               // ci*9 + tap
    int ij = vv % 9, ci = vv / 9;
    int row = r * 64 + oc * 8 + ci;
    float val = bb[row];
#pragma unroll
    for (int cc = 0; cc < 8; cc++) val += h[cc * 9 + ij] * wb[row * 8 + cc];
    Kg[(size_t)(b * 8 + r) * 576 + u] = val;
  }
}

// ---------------- conv + BN + ReLU ------------------------------------------
// One thread per pixel, 8 out channels. All 8 regions' K staged in LDS
// (region stride padded 576->584 floats: distinct-region lanes land 2-way max
// on banks, which is free). LAYER==1 computes & stores regmap from hist.
template <int LAYER>
__global__ __launch_bounds__(256) void conv_kernel(
    const float* __restrict__ x, const float* __restrict__ hist,
    const unsigned char* __restrict__ regin, unsigned char* __restrict__ regout,
    const float* __restrict__ Kg,
    const float* __restrict__ g, const float* __restrict__ be,
    const float* __restrict__ m, const float* __restrict__ v,
    float* __restrict__ out) {
  __shared__ float Ks[8 * 584];
  __shared__ float bns[8], bnsh[8];
  int b = blockIdx.x >> 8;
  int pix = ((blockIdx.x & 255) << 8) | threadIdx.x;

  const float* Kb = Kg + (size_t)b * 4608;
  for (int t = threadIdx.x; t < 4608; t += 256) {
    int rr = t / 576;
    Ks[rr * 584 + (t - rr * 576)] = Kb[t];
  }
  if (threadIdx.x < 8) {
    float s = g[threadIdx.x] * rsqrtf(v[threadIdx.x] + 1e-5f);
    bns[threadIdx.x] = s;
    bnsh[threadIdx.x] = be[threadIdx.x] - m[threadIdx.x] * s;
  }
  __syncthreads();

  int y0 = pix >> 8, x0 = pix & 255;
  int reg;
  if (LAYER == 1) {
    const float* hp = hist + (size_t)b * 8 * HWPX + pix;
    float best = hp[0];
    reg = 0;
#pragma unroll
    for (int r = 1; r < 8; r++) {
      float hv = hp[(size_t)r * HWPX];
      if (hv > best) { best = hv; reg = r; }   // strict > == JAX first-max
    }
    regout[b * HWPX + pix] = (unsigned char)reg;
  } else {
    reg = regin[b * HWPX + pix];
  }

  const float* Kr = Ks + reg * 584;
  float acc[8] = {0.f, 0.f, 0.f, 0.f, 0.f, 0.f, 0.f, 0.f};
  const float* xb = x + (size_t)b * 8 * HWPX;
#pragma unroll
  for (int di = 0; di < 3; di++) {
    int yy = y0 + di - 1;
    if ((unsigned)yy >= 256u) continue;
#pragma unroll
    for (int dj = 0; dj < 3; dj++) {
      int xx = x0 + dj - 1;
      if ((unsigned)xx >= 256u) continue;
      const float* xp = xb + yy * HDIM + xx;
      const float* kk = Kr + (di * 3 + dj) * 8;
#pragma unroll
      for (int ci = 0; ci < 8; ci++) {
        float xv = xp[(size_t)ci * HWPX];
        const float* k2 = kk + ci * 72;
#pragma unroll
        for (int oc = 0; oc < 8; oc++) acc[oc] += xv * k2[oc];
      }
    }
  }

  float* op = out + (size_t)b * 8 * HWPX + pix;
#pragma unroll
  for (int oc = 0; oc < 8; oc++) {
    float rv = acc[oc] * bns[oc] + bnsh[oc];
    op[(size_t)oc * HWPX] = fmaxf(rv, 0.f);
  }
}

extern "C" void kernel_launch(void* const* d_in, const int* in_sizes, int n_in,
                              void* d_out, int out_size, void* d_ws, size_t ws_size,
                              hipStream_t stream) {
  const float* x    = (const float*)d_in[0];
  const float* hist = (const float*)d_in[1];
  const float* w1a  = (const float*)d_in[2];
  const float* b1a  = (const float*)d_in[3];
  const float* w1b  = (const float*)d_in[4];
  const float* b1b  = (const float*)d_in[5];
  const float* g1   = (const float*)d_in[6];
  const float* be1  = (const float*)d_in[7];
  const float* m1   = (const float*)d_in[8];
  const float* v1   = (const float*)d_in[9];
  const float* w2a  = (const float*)d_in[10];
  const float* b2a  = (const float*)d_in[11];
  const float* w2b  = (const float*)d_in[12];
  const float* b2b  = (const float*)d_in[13];
  const float* g2   = (const float*)d_in[14];
  const float* be2  = (const float*)d_in[15];
  const float* m2   = (const float*)d_in[16];
  const float* v2   = (const float*)d_in[17];
  float* outp = (float*)d_out;

  char* ws = (char*)d_ws;
  unsigned char* regmap = (unsigned char*)ws;          // 524288 B
  float* pbuf = (float*)(ws + 524288);                 // 2304 B (reused L1/L2)
  float* Kg1  = (float*)(ws + 526592);                 // 147456 B
  float* Kg2  = (float*)(ws + 674048);                 // 147456 B
  float* y1   = (float*)(ws + 821504);                 // 16 MiB

  pool_kernel<<<576, 256, 0, stream>>>(x, pbuf);
  make_kernels<<<64, 128, 0, stream>>>(pbuf, w1a, b1a, w1b, b1b, Kg1);
  conv_kernel<1><<<2048, 256, 0, stream>>>(x, hist, nullptr, regmap, Kg1,
                                           g1, be1, m1, v1, y1);
  pool_kernel<<<576, 256, 0, stream>>>(y1, pbuf);
  make_kernels<<<64, 128, 0, stream>>>(pbuf, w2a, b2a, w2b, b2b, Kg2);
  conv_kernel<2><<<2048, 256, 0, stream>>>(y1, nullptr, regmap, nullptr, Kg2,
                                           g2, be2, m2, v2, outp);
}